// Round 13
// baseline (1274.055 us; speedup 1.0000x reference)
//
#include <hip/hip_runtime.h>

#define kB 4
#define kC 128
#define kN 4096
#define kD 32
#define kL 5
#define kCO 640
#define kL2E 1.4426950408889634f

typedef float f32x4 __attribute__((ext_vector_type(4)));
typedef short bf16x4 __attribute__((ext_vector_type(4)));
typedef short bf16x8 __attribute__((ext_vector_type(8)));
typedef unsigned u32;
typedef u32 u32x4 __attribute__((ext_vector_type(4)));
typedef unsigned short u16;

__device__ __forceinline__ float bf2f(u16 u) {
  unsigned v = ((unsigned)u) << 16;
  return __builtin_bit_cast(float, v);
}
__device__ __forceinline__ u16 f2bf(float f) {
  unsigned u = __builtin_bit_cast(unsigned, f);
  u += 0x7fffu + ((u >> 16) & 1u);
  return (u16)(u >> 16);
}
__device__ __forceinline__ void split2(float v, u16& hi, u16& lo) {
  hi = f2bf(v);
  lo = f2bf(v - bf2f(hi));
}
// pack 2 fp32 -> 1 u32 of 2 bf16 (word.lo = bf16(a), word.hi = bf16(b))
__device__ __forceinline__ u32 cvtpk(float a, float b) {
  u32 r;
  asm("v_cvt_pk_bf16_f32 %0, %1, %2" : "=v"(r) : "v"(a), "v"(b));
  return r;
}
// split pair into hi-word and lo-word (lo absorbs hi's rounding; split identity holds)
__device__ __forceinline__ void splitpk(float a, float b, u32& hw, u32& lw) {
  hw = cvtpk(a, b);
  float ha = __builtin_bit_cast(float, hw << 16);
  float hb = __builtin_bit_cast(float, hw & 0xffff0000u);
  lw = cvtpk(a - ha, b - hb);
}
// s += A*B with split operands: ah*bh + ah*bl + al*bh (drops al*bl, ~2^-16 rel)
__device__ __forceinline__ f32x4 mfma3(bf16x8 ah, bf16x8 al, bf16x8 bh, bf16x8 bl, f32x4 c) {
  c = __builtin_amdgcn_mfma_f32_16x16x32_bf16(ah, bh, c, 0, 0, 0);
  c = __builtin_amdgcn_mfma_f32_16x16x32_bf16(ah, bl, c, 0, 0, 0);
  c = __builtin_amdgcn_mfma_f32_16x16x32_bf16(al, bh, c, 0, 0, 0);
  return c;
}

// ---------------- sentinel (ws too small): encodes ws MB into output
__global__ void sentinel_kernel(float* out, float val, int total) {
  int i = blockIdx.x * 256 + threadIdx.x;
  if (i < total) out[i] = val;
}

// ---------------- split fp32 weights -> bf16 hi/lo arenas
__global__ void cvt_split_kernel(const float* __restrict__ src, u16* __restrict__ dh,
                                 u16* __restrict__ dl, int count) {
  int i = blockIdx.x * 256 + threadIdx.x;
  if (i < count) {
    u16 h, l;
    split2(src[i], h, l);
    dh[i] = h;
    dl[i] = l;
  }
}

// ---------------- xh/xl[b][n][c] = split(h[b][c][n])   (transpose + split; setup only)
__global__ __launch_bounds__(256) void prep_kernel(
    const float* __restrict__ h, long hstride, long hoff,
    u16* __restrict__ xh, u16* __restrict__ xl) {
  __shared__ float t[32][33];
  int n0 = blockIdx.x * 32, c0 = blockIdx.y * 32, b = blockIdx.z;
  int tx = threadIdx.x & 31, ty = threadIdx.x >> 5;  // 32 x 8
#pragma unroll
  for (int i = 0; i < 4; ++i) {
    int c = c0 + ty + i * 8;
    t[ty + i * 8][tx] = h[(size_t)b * hstride + hoff + (size_t)c * kN + n0 + tx];
  }
  __syncthreads();
#pragma unroll
  for (int i = 0; i < 4; ++i) {
    int n = n0 + ty + i * 8, c = c0 + tx;
    u16 hh, ll;
    split2(t[tx][ty + i * 8], hh, ll);
    size_t idx = ((size_t)b * kN + n) * kC + c;
    xh[idx] = hh;
    xl[idx] = ll;
  }
}

// ---------------- QV GEMM: 5 waves x 2 tiles, 16 n-cols per block.
// V written in FRAGMENT-PACKED layout: Vp[b][nt=n/32][ct=c/16][lane][8 bf16],
// lane=(g<<4)|col holds V[ct*16+col][nt*32+4g..+3] (p=0) and [nt*32+16+4g..+3] (p=1).
__global__ __launch_bounds__(320) void qv_kernel(
    const u16* __restrict__ xh, const u16* __restrict__ xl,
    const u16* __restrict__ wqkh, const u16* __restrict__ wqkl,
    const u16* __restrict__ wvh, const u16* __restrict__ wvl,
    const float* __restrict__ bv,
    u16* __restrict__ Qh, u16* __restrict__ Ql,
    u16* __restrict__ Vph, u16* __restrict__ Vpl) {
  __shared__ float vt[4][2][16][17];
  int wave = threadIdx.x >> 6, lane = threadIdx.x & 63;  // wave 0..4
  int b = blockIdx.y;
  int n0 = blockIdx.x * 16;
  int col = lane & 15, g = lane >> 4;
  f32x4 acc[2] = {};
  const u16* xrh = xh + ((size_t)b * kN + n0 + col) * kC + g * 8;
  const u16* xrl = xl + ((size_t)b * kN + n0 + col) * kC + g * 8;
#pragma unroll
  for (int kk = 0; kk < 4; ++kk) {
    bf16x8 bh = *(const bf16x8*)(xrh + kk * 32);
    bf16x8 bl = *(const bf16x8*)(xrl + kk * 32);
#pragma unroll
    for (int i = 0; i < 2; ++i) {
      int ot = wave * 2 + i;
      size_t wi = (ot < 2) ? ((size_t)(ot * 16 + col) * kC) : ((size_t)((ot - 2) * 16 + col) * kC);
      const u16* wsh = (ot < 2) ? (wqkh + wi) : (wvh + wi);
      const u16* wsl = (ot < 2) ? (wqkl + wi) : (wvl + wi);
      bf16x8 ah = *(const bf16x8*)(wsh + kk * 32 + g * 8);
      bf16x8 al = *(const bf16x8*)(wsl + kk * 32 + g * 8);
      acc[i] = mfma3(ah, al, bh, bl, acc[i]);
    }
  }
  if (wave > 0) {
#pragma unroll
    for (int i = 0; i < 2; ++i) {
      int ct = wave * 2 + i - 2;
#pragma unroll
      for (int r = 0; r < 4; ++r)
        vt[wave - 1][i][4 * g + r][col] = acc[i][r] + bv[ct * 16 + 4 * g + r];
    }
  }
  __syncthreads();
  if (wave == 0) {
#pragma unroll
    for (int i = 0; i < 2; ++i) {
#pragma unroll
      for (int r = 0; r < 4; ++r) {
        int d = i * 16 + 4 * g + r;
        u16 hh, ll;
        split2(acc[i][r], hh, ll);
        size_t idx = ((size_t)b * kN + n0 + col) * kD + d;
        Qh[idx] = hh;
        Ql[idx] = ll;
      }
    }
  } else {
    int nt = n0 >> 5, p = (n0 >> 4) & 1;
#pragma unroll
    for (int i = 0; i < 2; ++i) {
      int ct = wave * 2 + i - 2;
      bf16x4 vh4, vl4;
#pragma unroll
      for (int j = 0; j < 4; ++j) {
        float v = vt[wave - 1][i][col][4 * g + j];
        u16 hh, ll;
        split2(v, hh, ll);
        vh4[j] = (short)hh;
        vl4[j] = (short)ll;
      }
      size_t base = ((((size_t)b * (kN / 32) + nt) * 8 + ct) * 64 + lane) * 8 + p * 4;
      *(bf16x4*)(Vph + base) = vh4;
      *(bf16x4*)(Vpl + base) = vl4;
    }
  }
}

// ---------------- pass1: 4 waves split the m-loop; online merge via LDS
__global__ __launch_bounds__(256) void pass1_kernel(
    const u16* __restrict__ Qh, const u16* __restrict__ Ql,
    float* __restrict__ rm2, float* __restrict__ rinv) {
  __shared__ float mxs[4][16], sms[4][16];
  int wave = threadIdx.x >> 6, lane = threadIdx.x & 63;
  int b = blockIdx.y;
  int n0 = blockIdx.x * 16;
  int col = lane & 15, g = lane >> 4;
  const u16* qbh = Qh + (size_t)b * kN * kD;
  const u16* qbl = Ql + (size_t)b * kN * kD;
  bf16x8 ah = *(const bf16x8*)(qbh + (size_t)(n0 + col) * kD + g * 8);
  bf16x8 al = *(const bf16x8*)(qbl + (size_t)(n0 + col) * kD + g * 8);
  float mx[4] = {-3.0e38f, -3.0e38f, -3.0e38f, -3.0e38f};
  float sm[4] = {0.f, 0.f, 0.f, 0.f};
#pragma unroll 1
  for (int m0 = wave * 16; m0 < kN; m0 += 64) {
    bf16x8 bh = *(const bf16x8*)(qbh + (size_t)(m0 + col) * kD + g * 8);
    bf16x8 bl = *(const bf16x8*)(qbl + (size_t)(m0 + col) * kD + g * 8);
    f32x4 s = {};
    s = mfma3(ah, al, bh, bl, s);
#pragma unroll
    for (int r = 0; r < 4; ++r) {
      float nm = fmaxf(mx[r], s[r]);
      sm[r] = sm[r] * exp2f((mx[r] - nm) * kL2E) + exp2f((s[r] - nm) * kL2E);
      mx[r] = nm;
    }
  }
#pragma unroll
  for (int o = 1; o < 16; o <<= 1) {
#pragma unroll
    for (int r = 0; r < 4; ++r) {
      float Mo = __shfl_xor(mx[r], o, 64);
      float So = __shfl_xor(sm[r], o, 64);
      float nm = fmaxf(mx[r], Mo);
      sm[r] = sm[r] * exp2f((mx[r] - nm) * kL2E) + So * exp2f((Mo - nm) * kL2E);
      mx[r] = nm;
    }
  }
  if (col == 0) {
#pragma unroll
    for (int r = 0; r < 4; ++r) {
      mxs[wave][4 * g + r] = mx[r];
      sms[wave][4 * g + r] = sm[r];
    }
  }
  __syncthreads();
  if (threadIdx.x < 16) {
    int t = threadIdx.x;
    float M = mxs[0][t], S = sms[0][t];
#pragma unroll
    for (int w = 1; w < 4; ++w) {
      float Mo = mxs[w][t], So = sms[w][t];
      float nm = fmaxf(M, Mo);
      S = S * exp2f((M - nm) * kL2E) + So * exp2f((Mo - nm) * kL2E);
      M = nm;
    }
    rm2[(size_t)b * kN + n0 + t] = M * kL2E;
    rinv[(size_t)b * kN + n0 + t] = 1.0f / S;
  }
}

// ---------------- pass2 v5: block m-32, 2 m-frags/wave (V register-reuse),
// P-split via v_cvt_pk_bf16_f32; no in-loop barriers; LDS end-combine.
__global__ __launch_bounds__(256) void pass2_kernel(
    const u16* __restrict__ Qh, const u16* __restrict__ Ql,
    const u16* __restrict__ Vph, const u16* __restrict__ Vpl,
    const float* __restrict__ rm2, const float* __restrict__ rinv,
    const u16* __restrict__ xh, const u16* __restrict__ xl,
    u16* __restrict__ yth, u16* __restrict__ ytl) {
  __shared__ f32x4 accs[4][8][64];
  __shared__ float csl[2][4][16];
  int wave = threadIdx.x >> 6, lane = threadIdx.x & 63;
  int b = blockIdx.y;
  int m0 = blockIdx.x * 32;
  int col = lane & 15, g = lane >> 4;
  const u16* qbh = Qh + (size_t)b * kN * kD;
  const u16* qbl = Ql + (size_t)b * kN * kD;
  const float* rmb = rm2 + (size_t)b * kN;
  const float* rib = rinv + (size_t)b * kN;
  bf16x8 bmh0 = *(const bf16x8*)(qbh + (size_t)(m0 + col) * kD + g * 8);
  bf16x8 bml0 = *(const bf16x8*)(qbl + (size_t)(m0 + col) * kD + g * 8);
  bf16x8 bmh1 = *(const bf16x8*)(qbh + (size_t)(m0 + 16 + col) * kD + g * 8);
  bf16x8 bml1 = *(const bf16x8*)(qbl + (size_t)(m0 + 16 + col) * kD + g * 8);
  const u16* vbh = Vph + (size_t)b * (kN / 32) * 4096;
  const u16* vbl = Vpl + (size_t)b * (kN / 32) * 4096;
  f32x4 accA[8] = {}, accB[8] = {};
  float csA = 0.f, csB = 0.f;
#pragma unroll 1
  for (int nn = wave * 32; nn < kN; nn += 128) {
    bf16x8 ah0 = *(const bf16x8*)(qbh + (size_t)(nn + col) * kD + g * 8);
    bf16x8 al0 = *(const bf16x8*)(qbl + (size_t)(nn + col) * kD + g * 8);
    bf16x8 ah1 = *(const bf16x8*)(qbh + (size_t)(nn + 16 + col) * kD + g * 8);
    bf16x8 al1 = *(const bf16x8*)(qbl + (size_t)(nn + 16 + col) * kD + g * 8);
    f32x4 sA0 = {}, sA1 = {}, sB0 = {}, sB1 = {};
    sA0 = mfma3(ah0, al0, bmh0, bml0, sA0);
    sA1 = mfma3(ah1, al1, bmh0, bml0, sA1);
    sB0 = mfma3(ah0, al0, bmh1, bml1, sB0);
    sB1 = mfma3(ah1, al1, bmh1, bml1, sB1);
    float pA[8], pB[8];
#pragma unroll
    for (int r = 0; r < 4; ++r) {
      float e0 = rmb[nn + 4 * g + r], i0 = rib[nn + 4 * g + r];
      float e1 = rmb[nn + 16 + 4 * g + r], i1 = rib[nn + 16 + 4 * g + r];
      pA[r] = exp2f(sA0[r] * kL2E - e0) * i0;
      pA[r + 4] = exp2f(sA1[r] * kL2E - e1) * i1;
      pB[r] = exp2f(sB0[r] * kL2E - e0) * i0;
      pB[r + 4] = exp2f(sB1[r] * kL2E - e1) * i1;
      csA += pA[r] + pA[r + 4];
      csB += pB[r] + pB[r + 4];
    }
    u32x4 Ahw, Alw, Bhw, Blw;
#pragma unroll
    for (int k2 = 0; k2 < 4; ++k2) {
      u32 h0, l0, h1, l1;
      splitpk(pA[2 * k2], pA[2 * k2 + 1], h0, l0);
      splitpk(pB[2 * k2], pB[2 * k2 + 1], h1, l1);
      Ahw[k2] = h0; Alw[k2] = l0;
      Bhw[k2] = h1; Blw[k2] = l1;
    }
    bf16x8 bAh = __builtin_bit_cast(bf16x8, Ahw);
    bf16x8 bAl = __builtin_bit_cast(bf16x8, Alw);
    bf16x8 bBh = __builtin_bit_cast(bf16x8, Bhw);
    bf16x8 bBl = __builtin_bit_cast(bf16x8, Blw);
    size_t vtile = (size_t)(nn >> 5) * 4096;
#pragma unroll
    for (int ct = 0; ct < 8; ++ct) {
      size_t off = vtile + ((size_t)ct * 64 + lane) * 8;
      bf16x8 a8h = *(const bf16x8*)(vbh + off);
      bf16x8 a8l = *(const bf16x8*)(vbl + off);
      accA[ct] = mfma3(a8h, a8l, bAh, bAl, accA[ct]);
      accB[ct] = mfma3(a8h, a8l, bBh, bBl, accB[ct]);
    }
  }
  csA += __shfl_xor(csA, 16, 64);
  csA += __shfl_xor(csA, 32, 64);
  csB += __shfl_xor(csB, 16, 64);
  csB += __shfl_xor(csB, 32, 64);
  if (lane < 16) {
    csl[0][wave][lane] = csA;
    csl[1][wave][lane] = csB;
  }
  // ---- phase A combine + write (rows m0+col)
#pragma unroll
  for (int ct = 0; ct < 8; ++ct) accs[wave][ct][lane] = accA[ct];
  __syncthreads();
  {
    float inv = 1.0f / (1e-9f + csl[0][0][col] + csl[0][1][col] + csl[0][2][col] + csl[0][3][col]);
    const u16* xrh = xh + ((size_t)b * kN + m0 + col) * kC;
    const u16* xrl = xl + ((size_t)b * kN + m0 + col) * kC;
#pragma unroll
    for (int i = 0; i < 2; ++i) {
      int ct = wave * 2 + i;
      f32x4 a = accs[0][ct][lane];
      a += accs[1][ct][lane];
      a += accs[2][ct][lane];
      a += accs[3][ct][lane];
      bf16x4 xvh = *(const bf16x4*)(xrh + ct * 16 + 4 * g);
      bf16x4 xvl = *(const bf16x4*)(xrl + ct * 16 + 4 * g);
#pragma unroll
      for (int r = 0; r < 4; ++r) {
        float xv = bf2f((u16)xvh[r]) + bf2f((u16)xvl[r]);
        float y = xv - a[r] * inv;
        u16 hh, ll;
        split2(y, hh, ll);
        size_t idx = ((size_t)b * kN + m0 + col) * kC + ct * 16 + 4 * g + r;
        yth[idx] = hh;
        ytl[idx] = ll;
      }
    }
  }
  __syncthreads();
  // ---- phase B combine + write (rows m0+16+col)
#pragma unroll
  for (int ct = 0; ct < 8; ++ct) accs[wave][ct][lane] = accB[ct];
  __syncthreads();
  {
    float inv = 1.0f / (1e-9f + csl[1][0][col] + csl[1][1][col] + csl[1][2][col] + csl[1][3][col]);
    const u16* xrh = xh + ((size_t)b * kN + m0 + 16 + col) * kC;
    const u16* xrl = xl + ((size_t)b * kN + m0 + 16 + col) * kC;
#pragma unroll
    for (int i = 0; i < 2; ++i) {
      int ct = wave * 2 + i;
      f32x4 a = accs[0][ct][lane];
      a += accs[1][ct][lane];
      a += accs[2][ct][lane];
      a += accs[3][ct][lane];
      bf16x4 xvh = *(const bf16x4*)(xrh + ct * 16 + 4 * g);
      bf16x4 xvl = *(const bf16x4*)(xrl + ct * 16 + 4 * g);
#pragma unroll
      for (int r = 0; r < 4; ++r) {
        float xv = bf2f((u16)xvh[r]) + bf2f((u16)xvl[r]);
        float y = xv - a[r] * inv;
        u16 hh, ll;
        split2(y, hh, ll);
        size_t idx = ((size_t)b * kN + m0 + 16 + col) * kC + ct * 16 + 4 * g + r;
        yth[idx] = hh;
        ytl[idx] = ll;
      }
    }
  }
}

// ---------------- conv GEMM: 4 waves x 2 output-tiles, 16 n-cols per block
__global__ __launch_bounds__(256) void tconv_kernel(
    const u16* __restrict__ inh, const u16* __restrict__ inl,
    const u16* __restrict__ wh, const u16* __restrict__ wl,
    const float* __restrict__ bias, float* __restrict__ u,
    long ustride, long uoff) {
  int wave = threadIdx.x >> 6, lane = threadIdx.x & 63;
  int b = blockIdx.y;
  int n0 = blockIdx.x * 16;
  int col = lane & 15, g = lane >> 4;
  f32x4 acc[2] = {};
  const u16* xrh = inh + ((size_t)b * kN + n0 + col) * kC + g * 8;
  const u16* xrl = inl + ((size_t)b * kN + n0 + col) * kC + g * 8;
#pragma unroll
  for (int kk = 0; kk < 4; ++kk) {
    bf16x8 bh = *(const bf16x8*)(xrh + kk * 32);
    bf16x8 bl = *(const bf16x8*)(xrl + kk * 32);
#pragma unroll
    for (int i = 0; i < 2; ++i) {
      int ot = wave * 2 + i;
      bf16x8 ah = *(const bf16x8*)(wh + (size_t)(ot * 16 + col) * kC + kk * 32 + g * 8);
      bf16x8 al = *(const bf16x8*)(wl + (size_t)(ot * 16 + col) * kC + kk * 32 + g * 8);
      acc[i] = mfma3(ah, al, bh, bl, acc[i]);
    }
  }
#pragma unroll
  for (int i = 0; i < 2; ++i) {
    int ot = wave * 2 + i;
#pragma unroll
    for (int r = 0; r < 4; ++r) {
      int c = ot * 16 + 4 * g + r;
      float v = acc[i][r] + (bias ? bias[c] : 0.f);
      u[(size_t)b * ustride + uoff + (size_t)c * kN + n0 + col] = v;
    }
  }
}

// ---------------- BN stats, two-pass fp32 (u strided in d_out)
__global__ __launch_bounds__(256) void bn_stats_kernel(const float* __restrict__ u,
                                                       long ustride, long uoff,
                                                       float* __restrict__ stat) {
  int c = blockIdx.x;
  __shared__ float red[4];
  float s = 0.f;
  for (int i = threadIdx.x; i < kB * kN; i += 256) {
    int b = i >> 12, n = i & (kN - 1);
    s += u[(size_t)b * ustride + uoff + (size_t)c * kN + n];
  }
#pragma unroll
  for (int o = 1; o < 64; o <<= 1) s += __shfl_xor(s, o, 64);
  int wid = threadIdx.x >> 6, lane = threadIdx.x & 63;
  if (lane == 0) red[wid] = s;
  __syncthreads();
  float mean = (red[0] + red[1] + red[2] + red[3]) / (float)(kB * kN);
  __syncthreads();
  float ss = 0.f;
  for (int i = threadIdx.x; i < kB * kN; i += 256) {
    int b = i >> 12, n = i & (kN - 1);
    float d = u[(size_t)b * ustride + uoff + (size_t)c * kN + n] - mean;
    ss += d * d;
  }
#pragma unroll
  for (int o = 1; o < 64; o <<= 1) ss += __shfl_xor(ss, o, 64);
  if (lane == 0) red[wid] = ss;
  __syncthreads();
  if (threadIdx.x == 0) {
    float var = (red[0] + red[1] + red[2] + red[3]) / (float)(kB * kN);
    stat[c] = mean;
    stat[kC + c] = rsqrtf(var + 1e-5f);
  }
}

// ---------------- fused bn_final + next-layer prep:
// y = relu(BN(u)) [+ h + e]; out = y; xh/xl = split(y + e)  (transpose via LDS)
__global__ __launch_bounds__(256) void bnprep_kernel(
    const float* __restrict__ u, long ustride, long uoff,
    const float* __restrict__ stat,
    const float* __restrict__ g, const float* __restrict__ bb,
    const float* __restrict__ h, long hstride, long hoff, int use_res,
    const float* __restrict__ xyz, const float* __restrict__ pw,
    const float* __restrict__ pb,
    float* __restrict__ out, long ostride, long ooff,
    u16* __restrict__ xh, u16* __restrict__ xl) {
  __shared__ float t[32][33];
  int n0 = blockIdx.x * 32, c0 = blockIdx.y * 32, b = blockIdx.z;
  int tx = threadIdx.x & 31, ty = threadIdx.x >> 5;  // 32 x 8
  const float* xp = xyz + ((size_t)b * kN + n0 + tx) * 3;
  float xv0 = xp[0], xv1 = xp[1], xv2 = xp[2];
#pragma unroll
  for (int i = 0; i < 4; ++i) {
    int c = c0 + ty + i * 8;
    float e = pw[c * 3 + 0] * xv0 + pw[c * 3 + 1] * xv1 + pw[c * 3 + 2] * xv2 + pb[c];
    float y = (u[(size_t)b * ustride + uoff + (size_t)c * kN + n0 + tx] - stat[c]) *
                  stat[kC + c] * g[c] + bb[c];
    y = fmaxf(y, 0.f);
    if (use_res) y += h[(size_t)b * hstride + hoff + (size_t)c * kN + n0 + tx] + e;
    out[(size_t)b * ostride + ooff + (size_t)c * kN + n0 + tx] = y;
    t[ty + i * 8][tx] = y + e;  // next layer's xa
  }
  __syncthreads();
#pragma unroll
  for (int i = 0; i < 4; ++i) {
    int n = n0 + ty + i * 8, c = c0 + tx;
    u16 hh, ll;
    split2(t[tx][ty + i * 8], hh, ll);
    size_t idx = ((size_t)b * kN + n) * kC + c;
    xh[idx] = hh;
    xl[idx] = ll;
  }
}

extern "C" void kernel_launch(void* const* d_in, const int* in_sizes, int n_in,
                              void* d_out, int out_size, void* d_ws, size_t ws_size,
                              hipStream_t stream) {
  const float* x = (const float*)d_in[0];
  const float* xyz = (const float*)d_in[1];
  const float* conv1_w = (const float*)d_in[2];
  const float* bn1_g = (const float*)d_in[3];
  const float* bn1_b = (const float*)d_in[4];
  const float* pos_w = (const float*)d_in[5];
  const float* pos_b = (const float*)d_in[6];
  const float* sa_wqk = (const float*)d_in[7];
  const float* sa_wv = (const float*)d_in[8];
  const float* sa_bv = (const float*)d_in[9];
  const float* sa_wt = (const float*)d_in[10];
  const float* sa_bt = (const float*)d_in[11];
  const float* sa_bng = (const float*)d_in[12];
  const float* sa_bnb = (const float*)d_in[13];
  float* out = (float*)d_out;
  char* ws = (char*)d_ws;
  const size_t MB = (size_t)1 << 20;

  const size_t NEED = 28 * MB;
  if (ws_size < NEED) {
    float val = 100.0f + (float)(ws_size >> 20);
    sentinel_kernel<<<dim3((out_size + 255) / 256), dim3(256), 0, stream>>>(out, val, out_size);
    return;
  }

  u16* xh = (u16*)(ws);                  // [0,4MB)
  u16* xl = (u16*)(ws + 4 * MB);         // [4,8MB)
  u16* yth = (u16*)(ws + 8 * MB);        // [8,12MB)
  u16* ytl = (u16*)(ws + 12 * MB);       // [12,16MB)
  u16* Vph = (u16*)(ws + 16 * MB);       // [16,20MB)  packed V hi
  u16* Vpl = (u16*)(ws + 20 * MB);       // [20,24MB)  packed V lo
  u16* Qh = (u16*)(ws + 24 * MB);        // [24,25MB)
  u16* Ql = (u16*)(ws + 25 * MB);        // [25,26MB)
  u16* wa = (u16*)(ws + 26 * MB);        // weight split arena [26,27MB)
  size_t woff = 0;
  u16* c1h = wa + woff; woff += 16384;
  u16* c1l = wa + woff; woff += 16384;
  u16* qkh = wa + woff; woff += 5 * 32 * 128;
  u16* qkl = wa + woff; woff += 5 * 32 * 128;
  u16* wvh = wa + woff; woff += 5 * 128 * 128;
  u16* wvl = wa + woff; woff += 5 * 128 * 128;
  u16* wth = wa + woff; woff += 5 * 128 * 128;
  u16* wtl = wa + woff; woff += 5 * 128 * 128;
  float* rm2 = (float*)(ws + 27 * MB);
  float* rinv = (float*)(ws + 27 * MB + 65536);
  float* stat = (float*)(ws + 27 * MB + 131072);

  dim3 blk(256);

  cvt_split_kernel<<<dim3(64), blk, 0, stream>>>(conv1_w, c1h, c1l, 16384);
  cvt_split_kernel<<<dim3(80), blk, 0, stream>>>(sa_wqk, qkh, qkl, 20480);
  cvt_split_kernel<<<dim3(320), blk, 0, stream>>>(sa_wv, wvh, wvl, 81920);
  cvt_split_kernel<<<dim3(320), blk, 0, stream>>>(sa_wt, wth, wtl, 81920);

  const long sbo = (long)kCO * kN;
  const long slice = (long)kC * kN;
  const long h0off = 4 * slice;  // h0 parked in layer-4 slice (dead after layer-0 reads)

  // ---- setup: conv1 + BN + relu -> h0; bnprep also emits layer-0 xa (h0 + emb)
  prep_kernel<<<dim3(kN / 32, kC / 32, kB), blk, 0, stream>>>(x, slice, 0, xh, xl);
  tconv_kernel<<<dim3(kN / 16, kB), blk, 0, stream>>>(
      xh, xl, c1h, c1l, nullptr, out, sbo, 0);
  bn_stats_kernel<<<dim3(kC), blk, 0, stream>>>(out, sbo, 0, stat);
  bnprep_kernel<<<dim3(kN / 32, kC / 32, kB), blk, 0, stream>>>(
      out, sbo, 0, stat, bn1_g, bn1_b, nullptr, 0, 0, 0, xyz, pos_w, pos_b,
      out, sbo, h0off, xh, xl);

  long hoff = h0off;
  for (int i = 0; i < kL; ++i) {
    long uoff = (long)i * slice;  // layer-i pre-BN u lives in out slice i (in-place BN)
    qv_kernel<<<dim3(kN / 16, kB), dim3(320), 0, stream>>>(
        xh, xl, qkh + (size_t)i * kD * kC, qkl + (size_t)i * kD * kC,
        wvh + (size_t)i * kC * kC, wvl + (size_t)i * kC * kC,
        sa_bv + (size_t)i * kC, Qh, Ql, Vph, Vpl);
    pass1_kernel<<<dim3(kN / 16, kB), blk, 0, stream>>>(Qh, Ql, rm2, rinv);
    pass2_kernel<<<dim3(kN / 32, kB), blk, 0, stream>>>(
        Qh, Ql, Vph, Vpl, rm2, rinv, xh, xl, yth, ytl);
    tconv_kernel<<<dim3(kN / 16, kB), blk, 0, stream>>>(
        yth, ytl, wth + (size_t)i * kC * kC, wtl + (size_t)i * kC * kC,
        sa_bt + (size_t)i * kC, out, sbo, uoff);
    bn_stats_kernel<<<dim3(kC), blk, 0, stream>>>(out, sbo, uoff, stat);
    bnprep_kernel<<<dim3(kN / 32, kC / 32, kB), blk, 0, stream>>>(
        out, sbo, uoff, stat, sa_bng + (size_t)i * kC, sa_bnb + (size_t)i * kC,
        out, sbo, hoff, 1, xyz, pos_w, pos_b, out, sbo, uoff, xh, xl);
    hoff = uoff;
  }
}

// Round 14
// 1048.400 us; speedup vs baseline: 1.2152x; 1.2152x over previous
//
#include <hip/hip_runtime.h>

#define kB 4
#define kC 128
#define kN 4096
#define kD 32
#define kL 5
#define kCO 640
#define kL2E 1.4426950408889634f

typedef float f32x4 __attribute__((ext_vector_type(4)));
typedef short bf16x4 __attribute__((ext_vector_type(4)));
typedef short bf16x8 __attribute__((ext_vector_type(8)));
typedef unsigned u32;
typedef unsigned short u16;

__device__ __forceinline__ float bf2f(u16 u) {
  unsigned v = ((unsigned)u) << 16;
  return __builtin_bit_cast(float, v);
}
__device__ __forceinline__ u16 f2bf(float f) {
  unsigned u = __builtin_bit_cast(unsigned, f);
  u += 0x7fffu + ((u >> 16) & 1u);
  return (u16)(u >> 16);
}
__device__ __forceinline__ void split2(float v, u16& hi, u16& lo) {
  hi = f2bf(v);
  lo = f2bf(v - bf2f(hi));
}
// truncation split (cheap): hi=trunc(v), lo=trunc(v-hi). lo absorbs hi's trunc
// error exactly; residual ~2^-16 rel — used only for P (>=0) in pass2.
__device__ __forceinline__ void split2t(float v, u16& hi, u16& lo) {
  u32 u = __builtin_bit_cast(u32, v);
  hi = (u16)(u >> 16);
  float hf = __builtin_bit_cast(float, u & 0xffff0000u);
  float l = v - hf;
  lo = (u16)(__builtin_bit_cast(u32, l) >> 16);
}
// s += A*B with split operands: ah*bh + ah*bl + al*bh (drops al*bl, ~2^-16 rel)
__device__ __forceinline__ f32x4 mfma3(bf16x8 ah, bf16x8 al, bf16x8 bh, bf16x8 bl, f32x4 c) {
  c = __builtin_amdgcn_mfma_f32_16x16x32_bf16(ah, bh, c, 0, 0, 0);
  c = __builtin_amdgcn_mfma_f32_16x16x32_bf16(ah, bl, c, 0, 0, 0);
  c = __builtin_amdgcn_mfma_f32_16x16x32_bf16(al, bh, c, 0, 0, 0);
  return c;
}

// ---------------- sentinel (ws too small): encodes ws MB into output
__global__ void sentinel_kernel(float* out, float val, int total) {
  int i = blockIdx.x * 256 + threadIdx.x;
  if (i < total) out[i] = val;
}

// ---------------- split fp32 weights -> bf16 hi/lo arenas
__global__ void cvt_split_kernel(const float* __restrict__ src, u16* __restrict__ dh,
                                 u16* __restrict__ dl, int count) {
  int i = blockIdx.x * 256 + threadIdx.x;
  if (i < count) {
    u16 h, l;
    split2(src[i], h, l);
    dh[i] = h;
    dl[i] = l;
  }
}

// ---------------- xh/xl[b][n][c] = split(h[b][c][n])   (transpose + split; setup only)
__global__ __launch_bounds__(256) void prep_kernel(
    const float* __restrict__ h, long hstride, long hoff,
    u16* __restrict__ xh, u16* __restrict__ xl) {
  __shared__ float t[32][33];
  int n0 = blockIdx.x * 32, c0 = blockIdx.y * 32, b = blockIdx.z;
  int tx = threadIdx.x & 31, ty = threadIdx.x >> 5;  // 32 x 8
#pragma unroll
  for (int i = 0; i < 4; ++i) {
    int c = c0 + ty + i * 8;
    t[ty + i * 8][tx] = h[(size_t)b * hstride + hoff + (size_t)c * kN + n0 + tx];
  }
  __syncthreads();
#pragma unroll
  for (int i = 0; i < 4; ++i) {
    int n = n0 + ty + i * 8, c = c0 + tx;
    u16 hh, ll;
    split2(t[tx][ty + i * 8], hh, ll);
    size_t idx = ((size_t)b * kN + n) * kC + c;
    xh[idx] = hh;
    xl[idx] = ll;
  }
}

// ---------------- QV GEMM: 5 waves x 2 tiles, 16 n-cols per block.
// V written in FRAGMENT-PACKED layout: Vp[b][nt=n/32][ct=c/16][lane][8 bf16],
// lane=(g<<4)|col holds V[ct*16+col][nt*32+4g..+3] (p=0) and [nt*32+16+4g..+3] (p=1).
__global__ __launch_bounds__(320) void qv_kernel(
    const u16* __restrict__ xh, const u16* __restrict__ xl,
    const u16* __restrict__ wqkh, const u16* __restrict__ wqkl,
    const u16* __restrict__ wvh, const u16* __restrict__ wvl,
    const float* __restrict__ bv,
    u16* __restrict__ Qh, u16* __restrict__ Ql,
    u16* __restrict__ Vph, u16* __restrict__ Vpl) {
  __shared__ float vt[4][2][16][17];
  int wave = threadIdx.x >> 6, lane = threadIdx.x & 63;  // wave 0..4
  int b = blockIdx.y;
  int n0 = blockIdx.x * 16;
  int col = lane & 15, g = lane >> 4;
  f32x4 acc[2] = {};
  const u16* xrh = xh + ((size_t)b * kN + n0 + col) * kC + g * 8;
  const u16* xrl = xl + ((size_t)b * kN + n0 + col) * kC + g * 8;
#pragma unroll
  for (int kk = 0; kk < 4; ++kk) {
    bf16x8 bh = *(const bf16x8*)(xrh + kk * 32);
    bf16x8 bl = *(const bf16x8*)(xrl + kk * 32);
#pragma unroll
    for (int i = 0; i < 2; ++i) {
      int ot = wave * 2 + i;
      size_t wi = (ot < 2) ? ((size_t)(ot * 16 + col) * kC) : ((size_t)((ot - 2) * 16 + col) * kC);
      const u16* wsh = (ot < 2) ? (wqkh + wi) : (wvh + wi);
      const u16* wsl = (ot < 2) ? (wqkl + wi) : (wvl + wi);
      bf16x8 ah = *(const bf16x8*)(wsh + kk * 32 + g * 8);
      bf16x8 al = *(const bf16x8*)(wsl + kk * 32 + g * 8);
      acc[i] = mfma3(ah, al, bh, bl, acc[i]);
    }
  }
  if (wave > 0) {
#pragma unroll
    for (int i = 0; i < 2; ++i) {
      int ct = wave * 2 + i - 2;
#pragma unroll
      for (int r = 0; r < 4; ++r)
        vt[wave - 1][i][4 * g + r][col] = acc[i][r] + bv[ct * 16 + 4 * g + r];
    }
  }
  __syncthreads();
  if (wave == 0) {
#pragma unroll
    for (int i = 0; i < 2; ++i) {
#pragma unroll
      for (int r = 0; r < 4; ++r) {
        int d = i * 16 + 4 * g + r;
        u16 hh, ll;
        split2(acc[i][r], hh, ll);
        size_t idx = ((size_t)b * kN + n0 + col) * kD + d;
        Qh[idx] = hh;
        Ql[idx] = ll;
      }
    }
  } else {
    int nt = n0 >> 5, p = (n0 >> 4) & 1;
#pragma unroll
    for (int i = 0; i < 2; ++i) {
      int ct = wave * 2 + i - 2;
      bf16x4 vh4, vl4;
#pragma unroll
      for (int j = 0; j < 4; ++j) {
        float v = vt[wave - 1][i][col][4 * g + j];
        u16 hh, ll;
        split2(v, hh, ll);
        vh4[j] = (short)hh;
        vl4[j] = (short)ll;
      }
      size_t base = ((((size_t)b * (kN / 32) + nt) * 8 + ct) * 64 + lane) * 8 + p * 4;
      *(bf16x4*)(Vph + base) = vh4;
      *(bf16x4*)(Vpl + base) = vl4;
    }
  }
}

// ---------------- pass1: 4 waves split the m-loop; online merge via LDS
__global__ __launch_bounds__(256) void pass1_kernel(
    const u16* __restrict__ Qh, const u16* __restrict__ Ql,
    float* __restrict__ rm2, float* __restrict__ rinv) {
  __shared__ float mxs[4][16], sms[4][16];
  int wave = threadIdx.x >> 6, lane = threadIdx.x & 63;
  int b = blockIdx.y;
  int n0 = blockIdx.x * 16;
  int col = lane & 15, g = lane >> 4;
  const u16* qbh = Qh + (size_t)b * kN * kD;
  const u16* qbl = Ql + (size_t)b * kN * kD;
  bf16x8 ah = *(const bf16x8*)(qbh + (size_t)(n0 + col) * kD + g * 8);
  bf16x8 al = *(const bf16x8*)(qbl + (size_t)(n0 + col) * kD + g * 8);
  float mx[4] = {-3.0e38f, -3.0e38f, -3.0e38f, -3.0e38f};
  float sm[4] = {0.f, 0.f, 0.f, 0.f};
#pragma unroll 1
  for (int m0 = wave * 16; m0 < kN; m0 += 64) {
    bf16x8 bh = *(const bf16x8*)(qbh + (size_t)(m0 + col) * kD + g * 8);
    bf16x8 bl = *(const bf16x8*)(qbl + (size_t)(m0 + col) * kD + g * 8);
    f32x4 s = {};
    s = mfma3(ah, al, bh, bl, s);
#pragma unroll
    for (int r = 0; r < 4; ++r) {
      float nm = fmaxf(mx[r], s[r]);
      sm[r] = sm[r] * exp2f((mx[r] - nm) * kL2E) + exp2f((s[r] - nm) * kL2E);
      mx[r] = nm;
    }
  }
#pragma unroll
  for (int o = 1; o < 16; o <<= 1) {
#pragma unroll
    for (int r = 0; r < 4; ++r) {
      float Mo = __shfl_xor(mx[r], o, 64);
      float So = __shfl_xor(sm[r], o, 64);
      float nm = fmaxf(mx[r], Mo);
      sm[r] = sm[r] * exp2f((mx[r] - nm) * kL2E) + So * exp2f((Mo - nm) * kL2E);
      mx[r] = nm;
    }
  }
  if (col == 0) {
#pragma unroll
    for (int r = 0; r < 4; ++r) {
      mxs[wave][4 * g + r] = mx[r];
      sms[wave][4 * g + r] = sm[r];
    }
  }
  __syncthreads();
  if (threadIdx.x < 16) {
    int t = threadIdx.x;
    float M = mxs[0][t], S = sms[0][t];
#pragma unroll
    for (int w = 1; w < 4; ++w) {
      float Mo = mxs[w][t], So = sms[w][t];
      float nm = fmaxf(M, Mo);
      S = S * exp2f((M - nm) * kL2E) + So * exp2f((Mo - nm) * kL2E);
      M = nm;
    }
    rm2[(size_t)b * kN + n0 + t] = M * kL2E;
    rinv[(size_t)b * kN + n0 + t] = 1.0f / S;
  }
}

// ---------------- pass2 v6: block m-32, 2 m-frags/wave (V register-reuse),
// P-split via scalar split2t (trunc; compiler-scheduled). No in-loop barriers.
__global__ __launch_bounds__(256) void pass2_kernel(
    const u16* __restrict__ Qh, const u16* __restrict__ Ql,
    const u16* __restrict__ Vph, const u16* __restrict__ Vpl,
    const float* __restrict__ rm2, const float* __restrict__ rinv,
    const u16* __restrict__ xh, const u16* __restrict__ xl,
    u16* __restrict__ yth, u16* __restrict__ ytl) {
  __shared__ f32x4 accs[4][8][64];
  __shared__ float csl[2][4][16];
  int wave = threadIdx.x >> 6, lane = threadIdx.x & 63;
  int b = blockIdx.y;
  int m0 = blockIdx.x * 32;
  int col = lane & 15, g = lane >> 4;
  const u16* qbh = Qh + (size_t)b * kN * kD;
  const u16* qbl = Ql + (size_t)b * kN * kD;
  const float* rmb = rm2 + (size_t)b * kN;
  const float* rib = rinv + (size_t)b * kN;
  bf16x8 bmh0 = *(const bf16x8*)(qbh + (size_t)(m0 + col) * kD + g * 8);
  bf16x8 bml0 = *(const bf16x8*)(qbl + (size_t)(m0 + col) * kD + g * 8);
  bf16x8 bmh1 = *(const bf16x8*)(qbh + (size_t)(m0 + 16 + col) * kD + g * 8);
  bf16x8 bml1 = *(const bf16x8*)(qbl + (size_t)(m0 + 16 + col) * kD + g * 8);
  const u16* vbh = Vph + (size_t)b * (kN / 32) * 4096;
  const u16* vbl = Vpl + (size_t)b * (kN / 32) * 4096;
  f32x4 accA[8] = {}, accB[8] = {};
  float csA = 0.f, csB = 0.f;
#pragma unroll 1
  for (int nn = wave * 32; nn < kN; nn += 128) {
    bf16x8 ah0 = *(const bf16x8*)(qbh + (size_t)(nn + col) * kD + g * 8);
    bf16x8 al0 = *(const bf16x8*)(qbl + (size_t)(nn + col) * kD + g * 8);
    bf16x8 ah1 = *(const bf16x8*)(qbh + (size_t)(nn + 16 + col) * kD + g * 8);
    bf16x8 al1 = *(const bf16x8*)(qbl + (size_t)(nn + 16 + col) * kD + g * 8);
    f32x4 sA0 = {}, sA1 = {}, sB0 = {}, sB1 = {};
    sA0 = mfma3(ah0, al0, bmh0, bml0, sA0);
    sA1 = mfma3(ah1, al1, bmh0, bml0, sA1);
    sB0 = mfma3(ah0, al0, bmh1, bml1, sB0);
    sB1 = mfma3(ah1, al1, bmh1, bml1, sB1);
    bf16x8 bAh, bAl, bBh, bBl;
#pragma unroll
    for (int r = 0; r < 4; ++r) {
      float e0 = rmb[nn + 4 * g + r], i0 = rib[nn + 4 * g + r];
      float e1 = rmb[nn + 16 + 4 * g + r], i1 = rib[nn + 16 + 4 * g + r];
      float pA0 = exp2f(sA0[r] * kL2E - e0) * i0;
      float pA1 = exp2f(sA1[r] * kL2E - e1) * i1;
      float pB0 = exp2f(sB0[r] * kL2E - e0) * i0;
      float pB1 = exp2f(sB1[r] * kL2E - e1) * i1;
      csA += pA0 + pA1;
      csB += pB0 + pB1;
      u16 hh, ll;
      split2t(pA0, hh, ll); bAh[r] = (short)hh; bAl[r] = (short)ll;
      split2t(pA1, hh, ll); bAh[r + 4] = (short)hh; bAl[r + 4] = (short)ll;
      split2t(pB0, hh, ll); bBh[r] = (short)hh; bBl[r] = (short)ll;
      split2t(pB1, hh, ll); bBh[r + 4] = (short)hh; bBl[r + 4] = (short)ll;
    }
    size_t vtile = (size_t)(nn >> 5) * 4096;
#pragma unroll
    for (int ct = 0; ct < 8; ++ct) {
      size_t off = vtile + ((size_t)ct * 64 + lane) * 8;
      bf16x8 a8h = *(const bf16x8*)(vbh + off);
      bf16x8 a8l = *(const bf16x8*)(vbl + off);
      accA[ct] = mfma3(a8h, a8l, bAh, bAl, accA[ct]);
      accB[ct] = mfma3(a8h, a8l, bBh, bBl, accB[ct]);
    }
  }
  csA += __shfl_xor(csA, 16, 64);
  csA += __shfl_xor(csA, 32, 64);
  csB += __shfl_xor(csB, 16, 64);
  csB += __shfl_xor(csB, 32, 64);
  if (lane < 16) {
    csl[0][wave][lane] = csA;
    csl[1][wave][lane] = csB;
  }
  // ---- phase A combine + write (rows m0+col)
#pragma unroll
  for (int ct = 0; ct < 8; ++ct) accs[wave][ct][lane] = accA[ct];
  __syncthreads();
  {
    float inv = 1.0f / (1e-9f + csl[0][0][col] + csl[0][1][col] + csl[0][2][col] + csl[0][3][col]);
    const u16* xrh = xh + ((size_t)b * kN + m0 + col) * kC;
    const u16* xrl = xl + ((size_t)b * kN + m0 + col) * kC;
#pragma unroll
    for (int i = 0; i < 2; ++i) {
      int ct = wave * 2 + i;
      f32x4 a = accs[0][ct][lane];
      a += accs[1][ct][lane];
      a += accs[2][ct][lane];
      a += accs[3][ct][lane];
      bf16x4 xvh = *(const bf16x4*)(xrh + ct * 16 + 4 * g);
      bf16x4 xvl = *(const bf16x4*)(xrl + ct * 16 + 4 * g);
#pragma unroll
      for (int r = 0; r < 4; ++r) {
        float xv = bf2f((u16)xvh[r]) + bf2f((u16)xvl[r]);
        float y = xv - a[r] * inv;
        u16 hh, ll;
        split2(y, hh, ll);
        size_t idx = ((size_t)b * kN + m0 + col) * kC + ct * 16 + 4 * g + r;
        yth[idx] = hh;
        ytl[idx] = ll;
      }
    }
  }
  __syncthreads();
  // ---- phase B combine + write (rows m0+16+col)
#pragma unroll
  for (int ct = 0; ct < 8; ++ct) accs[wave][ct][lane] = accB[ct];
  __syncthreads();
  {
    float inv = 1.0f / (1e-9f + csl[1][0][col] + csl[1][1][col] + csl[1][2][col] + csl[1][3][col]);
    const u16* xrh = xh + ((size_t)b * kN + m0 + 16 + col) * kC;
    const u16* xrl = xl + ((size_t)b * kN + m0 + 16 + col) * kC;
#pragma unroll
    for (int i = 0; i < 2; ++i) {
      int ct = wave * 2 + i;
      f32x4 a = accs[0][ct][lane];
      a += accs[1][ct][lane];
      a += accs[2][ct][lane];
      a += accs[3][ct][lane];
      bf16x4 xvh = *(const bf16x4*)(xrh + ct * 16 + 4 * g);
      bf16x4 xvl = *(const bf16x4*)(xrl + ct * 16 + 4 * g);
#pragma unroll
      for (int r = 0; r < 4; ++r) {
        float xv = bf2f((u16)xvh[r]) + bf2f((u16)xvl[r]);
        float y = xv - a[r] * inv;
        u16 hh, ll;
        split2(y, hh, ll);
        size_t idx = ((size_t)b * kN + m0 + 16 + col) * kC + ct * 16 + 4 * g + r;
        yth[idx] = hh;
        ytl[idx] = ll;
      }
    }
  }
}

// ---------------- conv GEMM: 4 waves x 2 output-tiles, 16 n-cols per block
__global__ __launch_bounds__(256) void tconv_kernel(
    const u16* __restrict__ inh, const u16* __restrict__ inl,
    const u16* __restrict__ wh, const u16* __restrict__ wl,
    const float* __restrict__ bias, float* __restrict__ u,
    long ustride, long uoff) {
  int wave = threadIdx.x >> 6, lane = threadIdx.x & 63;
  int b = blockIdx.y;
  int n0 = blockIdx.x * 16;
  int col = lane & 15, g = lane >> 4;
  f32x4 acc[2] = {};
  const u16* xrh = inh + ((size_t)b * kN + n0 + col) * kC + g * 8;
  const u16* xrl = inl + ((size_t)b * kN + n0 + col) * kC + g * 8;
#pragma unroll
  for (int kk = 0; kk < 4; ++kk) {
    bf16x8 bh = *(const bf16x8*)(xrh + kk * 32);
    bf16x8 bl = *(const bf16x8*)(xrl + kk * 32);
#pragma unroll
    for (int i = 0; i < 2; ++i) {
      int ot = wave * 2 + i;
      bf16x8 ah = *(const bf16x8*)(wh + (size_t)(ot * 16 + col) * kC + kk * 32 + g * 8);
      bf16x8 al = *(const bf16x8*)(wl + (size_t)(ot * 16 + col) * kC + kk * 32 + g * 8);
      acc[i] = mfma3(ah, al, bh, bl, acc[i]);
    }
  }
#pragma unroll
  for (int i = 0; i < 2; ++i) {
    int ot = wave * 2 + i;
#pragma unroll
    for (int r = 0; r < 4; ++r) {
      int c = ot * 16 + 4 * g + r;
      float v = acc[i][r] + (bias ? bias[c] : 0.f);
      u[(size_t)b * ustride + uoff + (size_t)c * kN + n0 + col] = v;
    }
  }
}

// ---------------- BN stats, two-pass fp32 (u strided in d_out)
__global__ __launch_bounds__(256) void bn_stats_kernel(const float* __restrict__ u,
                                                       long ustride, long uoff,
                                                       float* __restrict__ stat) {
  int c = blockIdx.x;
  __shared__ float red[4];
  float s = 0.f;
  for (int i = threadIdx.x; i < kB * kN; i += 256) {
    int b = i >> 12, n = i & (kN - 1);
    s += u[(size_t)b * ustride + uoff + (size_t)c * kN + n];
  }
#pragma unroll
  for (int o = 1; o < 64; o <<= 1) s += __shfl_xor(s, o, 64);
  int wid = threadIdx.x >> 6, lane = threadIdx.x & 63;
  if (lane == 0) red[wid] = s;
  __syncthreads();
  float mean = (red[0] + red[1] + red[2] + red[3]) / (float)(kB * kN);
  __syncthreads();
  float ss = 0.f;
  for (int i = threadIdx.x; i < kB * kN; i += 256) {
    int b = i >> 12, n = i & (kN - 1);
    float d = u[(size_t)b * ustride + uoff + (size_t)c * kN + n] - mean;
    ss += d * d;
  }
#pragma unroll
  for (int o = 1; o < 64; o <<= 1) ss += __shfl_xor(ss, o, 64);
  if (lane == 0) red[wid] = ss;
  __syncthreads();
  if (threadIdx.x == 0) {
    float var = (red[0] + red[1] + red[2] + red[3]) / (float)(kB * kN);
    stat[c] = mean;
    stat[kC + c] = rsqrtf(var + 1e-5f);
  }
}

// ---------------- fused bn_final + next-layer prep:
// y = relu(BN(u)) [+ h + e]; out = y; xh/xl = split(y + e)  (transpose via LDS)
__global__ __launch_bounds__(256) void bnprep_kernel(
    const float* __restrict__ u, long ustride, long uoff,
    const float* __restrict__ stat,
    const float* __restrict__ g, const float* __restrict__ bb,
    const float* __restrict__ h, long hstride, long hoff, int use_res,
    const float* __restrict__ xyz, const float* __restrict__ pw,
    const float* __restrict__ pb,
    float* __restrict__ out, long ostride, long ooff,
    u16* __restrict__ xh, u16* __restrict__ xl) {
  __shared__ float t[32][33];
  int n0 = blockIdx.x * 32, c0 = blockIdx.y * 32, b = blockIdx.z;
  int tx = threadIdx.x & 31, ty = threadIdx.x >> 5;  // 32 x 8
  const float* xp = xyz + ((size_t)b * kN + n0 + tx) * 3;
  float xv0 = xp[0], xv1 = xp[1], xv2 = xp[2];
#pragma unroll
  for (int i = 0; i < 4; ++i) {
    int c = c0 + ty + i * 8;
    float e = pw[c * 3 + 0] * xv0 + pw[c * 3 + 1] * xv1 + pw[c * 3 + 2] * xv2 + pb[c];
    float y = (u[(size_t)b * ustride + uoff + (size_t)c * kN + n0 + tx] - stat[c]) *
                  stat[kC + c] * g[c] + bb[c];
    y = fmaxf(y, 0.f);
    if (use_res) y += h[(size_t)b * hstride + hoff + (size_t)c * kN + n0 + tx] + e;
    out[(size_t)b * ostride + ooff + (size_t)c * kN + n0 + tx] = y;
    t[ty + i * 8][tx] = y + e;  // next layer's xa
  }
  __syncthreads();
#pragma unroll
  for (int i = 0; i < 4; ++i) {
    int n = n0 + ty + i * 8, c = c0 + tx;
    u16 hh, ll;
    split2(t[tx][ty + i * 8], hh, ll);
    size_t idx = ((size_t)b * kN + n) * kC + c;
    xh[idx] = hh;
    xl[idx] = ll;
  }
}

extern "C" void kernel_launch(void* const* d_in, const int* in_sizes, int n_in,
                              void* d_out, int out_size, void* d_ws, size_t ws_size,
                              hipStream_t stream) {
  const float* x = (const float*)d_in[0];
  const float* xyz = (const float*)d_in[1];
  const float* conv1_w = (const float*)d_in[2];
  const float* bn1_g = (const float*)d_in[3];
  const float* bn1_b = (const float*)d_in[4];
  const float* pos_w = (const float*)d_in[5];
  const float* pos_b = (const float*)d_in[6];
  const float* sa_wqk = (const float*)d_in[7];
  const float* sa_wv = (const float*)d_in[8];
  const float* sa_bv = (const float*)d_in[9];
  const float* sa_wt = (const float*)d_in[10];
  const float* sa_bt = (const float*)d_in[11];
  const float* sa_bng = (const float*)d_in[12];
  const float* sa_bnb = (const float*)d_in[13];
  float* out = (float*)d_out;
  char* ws = (char*)d_ws;
  const size_t MB = (size_t)1 << 20;

  const size_t NEED = 28 * MB;
  if (ws_size < NEED) {
    float val = 100.0f + (float)(ws_size >> 20);
    sentinel_kernel<<<dim3((out_size + 255) / 256), dim3(256), 0, stream>>>(out, val, out_size);
    return;
  }

  u16* xh = (u16*)(ws);                  // [0,4MB)
  u16* xl = (u16*)(ws + 4 * MB);         // [4,8MB)
  u16* yth = (u16*)(ws + 8 * MB);        // [8,12MB)
  u16* ytl = (u16*)(ws + 12 * MB);       // [12,16MB)
  u16* Vph = (u16*)(ws + 16 * MB);       // [16,20MB)  packed V hi
  u16* Vpl = (u16*)(ws + 20 * MB);       // [20,24MB)  packed V lo
  u16* Qh = (u16*)(ws + 24 * MB);        // [24,25MB)
  u16* Ql = (u16*)(ws + 25 * MB);        // [25,26MB)
  u16* wa = (u16*)(ws + 26 * MB);        // weight split arena [26,27MB)
  size_t woff = 0;
  u16* c1h = wa + woff; woff += 16384;
  u16* c1l = wa + woff; woff += 16384;
  u16* qkh = wa + woff; woff += 5 * 32 * 128;
  u16* qkl = wa + woff; woff += 5 * 32 * 128;
  u16* wvh = wa + woff; woff += 5 * 128 * 128;
  u16* wvl = wa + woff; woff += 5 * 128 * 128;
  u16* wth = wa + woff; woff += 5 * 128 * 128;
  u16* wtl = wa + woff; woff += 5 * 128 * 128;
  float* rm2 = (float*)(ws + 27 * MB);
  float* rinv = (float*)(ws + 27 * MB + 65536);
  float* stat = (float*)(ws + 27 * MB + 131072);

  dim3 blk(256);

  cvt_split_kernel<<<dim3(64), blk, 0, stream>>>(conv1_w, c1h, c1l, 16384);
  cvt_split_kernel<<<dim3(80), blk, 0, stream>>>(sa_wqk, qkh, qkl, 20480);
  cvt_split_kernel<<<dim3(320), blk, 0, stream>>>(sa_wv, wvh, wvl, 81920);
  cvt_split_kernel<<<dim3(320), blk, 0, stream>>>(sa_wt, wth, wtl, 81920);

  const long sbo = (long)kCO * kN;
  const long slice = (long)kC * kN;
  const long h0off = 4 * slice;  // h0 parked in layer-4 slice (dead after layer-0 reads)

  // ---- setup: conv1 + BN + relu -> h0; bnprep also emits layer-0 xa (h0 + emb)
  prep_kernel<<<dim3(kN / 32, kC / 32, kB), blk, 0, stream>>>(x, slice, 0, xh, xl);
  tconv_kernel<<<dim3(kN / 16, kB), blk, 0, stream>>>(
      xh, xl, c1h, c1l, nullptr, out, sbo, 0);
  bn_stats_kernel<<<dim3(kC), blk, 0, stream>>>(out, sbo, 0, stat);
  bnprep_kernel<<<dim3(kN / 32, kC / 32, kB), blk, 0, stream>>>(
      out, sbo, 0, stat, bn1_g, bn1_b, nullptr, 0, 0, 0, xyz, pos_w, pos_b,
      out, sbo, h0off, xh, xl);

  long hoff = h0off;
  for (int i = 0; i < kL; ++i) {
    long uoff = (long)i * slice;  // layer-i pre-BN u lives in out slice i (in-place BN)
    qv_kernel<<<dim3(kN / 16, kB), dim3(320), 0, stream>>>(
        xh, xl, qkh + (size_t)i * kD * kC, qkl + (size_t)i * kD * kC,
        wvh + (size_t)i * kC * kC, wvl + (size_t)i * kC * kC,
        sa_bv + (size_t)i * kC, Qh, Ql, Vph, Vpl);
    pass1_kernel<<<dim3(kN / 16, kB), blk, 0, stream>>>(Qh, Ql, rm2, rinv);
    pass2_kernel<<<dim3(kN / 32, kB), blk, 0, stream>>>(
        Qh, Ql, Vph, Vpl, rm2, rinv, xh, xl, yth, ytl);
    tconv_kernel<<<dim3(kN / 16, kB), blk, 0, stream>>>(
        yth, ytl, wth + (size_t)i * kC * kC, wtl + (size_t)i * kC * kC,
        sa_bt + (size_t)i * kC, out, sbo, uoff);
    bn_stats_kernel<<<dim3(kC), blk, 0, stream>>>(out, sbo, uoff, stat);
    bnprep_kernel<<<dim3(kN / 32, kC / 32, kB), blk, 0, stream>>>(
        out, sbo, uoff, stat, sa_bng + (size_t)i * kC, sa_bnb + (size_t)i * kC,
        out, sbo, hoff, 1, xyz, pos_w, pos_b, out, sbo, uoff, xh, xl);
    hoff = uoff;
  }
}

// Round 15
// 893.862 us; speedup vs baseline: 1.4253x; 1.1729x over previous
//
#include <hip/hip_runtime.h>

#define kB 4
#define kC 128
#define kN 4096
#define kD 32
#define kL 5
#define kCO 640
#define kL2E 1.4426950408889634f

typedef float f32x4 __attribute__((ext_vector_type(4)));
typedef short bf16x4 __attribute__((ext_vector_type(4)));
typedef short bf16x8 __attribute__((ext_vector_type(8)));
typedef unsigned u32;
typedef u32 u32x4 __attribute__((ext_vector_type(4)));
typedef unsigned short u16;

__device__ __forceinline__ float bf2f(u16 u) {
  unsigned v = ((unsigned)u) << 16;
  return __builtin_bit_cast(float, v);
}
__device__ __forceinline__ u16 f2bf(float f) {
  unsigned u = __builtin_bit_cast(unsigned, f);
  u += 0x7fffu + ((u >> 16) & 1u);
  return (u16)(u >> 16);
}
__device__ __forceinline__ void split2(float v, u16& hi, u16& lo) {
  hi = f2bf(v);
  lo = f2bf(v - bf2f(hi));
}
// raw v_exp_f32 (libm exp2f adds ~10 fixup ops without -ffast-math)
__device__ __forceinline__ float fexp2(float x) {
#if __has_builtin(__builtin_amdgcn_exp2f)
  return __builtin_amdgcn_exp2f(x);
#else
  return exp2f(x);
#endif
}
// pack pair (a,b) -> hi-word (trunc bf16s) and lo-word (trunc of residuals).
// word layout: lo16 = bf16(a) (even elem), hi16 = bf16(b) (odd elem).
// Bit-identical to split2t applied elementwise.
__device__ __forceinline__ void splitpair(float a, float b, u32& hw, u32& lw) {
  u32 ua = __builtin_bit_cast(u32, a), ub = __builtin_bit_cast(u32, b);
  u32 uam = ua & 0xffff0000u, ubm = ub & 0xffff0000u;
  hw = (ua >> 16) | ubm;
  float la = a - __builtin_bit_cast(float, uam);
  float lb = b - __builtin_bit_cast(float, ubm);
  lw = (__builtin_bit_cast(u32, la) >> 16) | (__builtin_bit_cast(u32, lb) & 0xffff0000u);
}
// s += A*B with split operands: ah*bh + ah*bl + al*bh (drops al*bl, ~2^-16 rel)
__device__ __forceinline__ f32x4 mfma3(bf16x8 ah, bf16x8 al, bf16x8 bh, bf16x8 bl, f32x4 c) {
  c = __builtin_amdgcn_mfma_f32_16x16x32_bf16(ah, bh, c, 0, 0, 0);
  c = __builtin_amdgcn_mfma_f32_16x16x32_bf16(ah, bl, c, 0, 0, 0);
  c = __builtin_amdgcn_mfma_f32_16x16x32_bf16(al, bh, c, 0, 0, 0);
  return c;
}

// ---------------- sentinel (ws too small): encodes ws MB into output
__global__ void sentinel_kernel(float* out, float val, int total) {
  int i = blockIdx.x * 256 + threadIdx.x;
  if (i < total) out[i] = val;
}

// ---------------- split fp32 weights -> bf16 hi/lo arenas
__global__ void cvt_split_kernel(const float* __restrict__ src, u16* __restrict__ dh,
                                 u16* __restrict__ dl, int count) {
  int i = blockIdx.x * 256 + threadIdx.x;
  if (i < count) {
    u16 h, l;
    split2(src[i], h, l);
    dh[i] = h;
    dl[i] = l;
  }
}

// ---------------- xh/xl[b][n][c] = split(h[b][c][n])   (transpose + split; setup only)
__global__ __launch_bounds__(256) void prep_kernel(
    const float* __restrict__ h, long hstride, long hoff,
    u16* __restrict__ xh, u16* __restrict__ xl) {
  __shared__ float t[32][33];
  int n0 = blockIdx.x * 32, c0 = blockIdx.y * 32, b = blockIdx.z;
  int tx = threadIdx.x & 31, ty = threadIdx.x >> 5;  // 32 x 8
#pragma unroll
  for (int i = 0; i < 4; ++i) {
    int c = c0 + ty + i * 8;
    t[ty + i * 8][tx] = h[(size_t)b * hstride + hoff + (size_t)c * kN + n0 + tx];
  }
  __syncthreads();
#pragma unroll
  for (int i = 0; i < 4; ++i) {
    int n = n0 + ty + i * 8, c = c0 + tx;
    u16 hh, ll;
    split2(t[tx][ty + i * 8], hh, ll);
    size_t idx = ((size_t)b * kN + n) * kC + c;
    xh[idx] = hh;
    xl[idx] = ll;
  }
}

// ---------------- QV GEMM: 5 waves x 2 tiles, 16 n-cols per block.
// V written in FRAGMENT-PACKED layout: Vp[b][nt=n/32][ct=c/16][lane][8 bf16],
// lane=(g<<4)|col holds V[ct*16+col][nt*32+4g..+3] (p=0) and [nt*32+16+4g..+3] (p=1).
__global__ __launch_bounds__(320) void qv_kernel(
    const u16* __restrict__ xh, const u16* __restrict__ xl,
    const u16* __restrict__ wqkh, const u16* __restrict__ wqkl,
    const u16* __restrict__ wvh, const u16* __restrict__ wvl,
    const float* __restrict__ bv,
    u16* __restrict__ Qh, u16* __restrict__ Ql,
    u16* __restrict__ Vph, u16* __restrict__ Vpl) {
  __shared__ float vt[4][2][16][17];
  int wave = threadIdx.x >> 6, lane = threadIdx.x & 63;  // wave 0..4
  int b = blockIdx.y;
  int n0 = blockIdx.x * 16;
  int col = lane & 15, g = lane >> 4;
  f32x4 acc[2] = {};
  const u16* xrh = xh + ((size_t)b * kN + n0 + col) * kC + g * 8;
  const u16* xrl = xl + ((size_t)b * kN + n0 + col) * kC + g * 8;
#pragma unroll
  for (int kk = 0; kk < 4; ++kk) {
    bf16x8 bh = *(const bf16x8*)(xrh + kk * 32);
    bf16x8 bl = *(const bf16x8*)(xrl + kk * 32);
#pragma unroll
    for (int i = 0; i < 2; ++i) {
      int ot = wave * 2 + i;
      size_t wi = (ot < 2) ? ((size_t)(ot * 16 + col) * kC) : ((size_t)((ot - 2) * 16 + col) * kC);
      const u16* wsh = (ot < 2) ? (wqkh + wi) : (wvh + wi);
      const u16* wsl = (ot < 2) ? (wqkl + wi) : (wvl + wi);
      bf16x8 ah = *(const bf16x8*)(wsh + kk * 32 + g * 8);
      bf16x8 al = *(const bf16x8*)(wsl + kk * 32 + g * 8);
      acc[i] = mfma3(ah, al, bh, bl, acc[i]);
    }
  }
  if (wave > 0) {
#pragma unroll
    for (int i = 0; i < 2; ++i) {
      int ct = wave * 2 + i - 2;
#pragma unroll
      for (int r = 0; r < 4; ++r)
        vt[wave - 1][i][4 * g + r][col] = acc[i][r] + bv[ct * 16 + 4 * g + r];
    }
  }
  __syncthreads();
  if (wave == 0) {
#pragma unroll
    for (int i = 0; i < 2; ++i) {
#pragma unroll
      for (int r = 0; r < 4; ++r) {
        int d = i * 16 + 4 * g + r;
        u16 hh, ll;
        split2(acc[i][r], hh, ll);
        size_t idx = ((size_t)b * kN + n0 + col) * kD + d;
        Qh[idx] = hh;
        Ql[idx] = ll;
      }
    }
  } else {
    int nt = n0 >> 5, p = (n0 >> 4) & 1;
#pragma unroll
    for (int i = 0; i < 2; ++i) {
      int ct = wave * 2 + i - 2;
      bf16x4 vh4, vl4;
#pragma unroll
      for (int j = 0; j < 4; ++j) {
        float v = vt[wave - 1][i][col][4 * g + j];
        u16 hh, ll;
        split2(v, hh, ll);
        vh4[j] = (short)hh;
        vl4[j] = (short)ll;
      }
      size_t base = ((((size_t)b * (kN / 32) + nt) * 8 + ct) * 64 + lane) * 8 + p * 4;
      *(bf16x4*)(Vph + base) = vh4;
      *(bf16x4*)(Vpl + base) = vl4;
    }
  }
}

// ---------------- pass1: 4 waves split the m-loop; online merge via LDS
__global__ __launch_bounds__(256) void pass1_kernel(
    const u16* __restrict__ Qh, const u16* __restrict__ Ql,
    float* __restrict__ rm2, float* __restrict__ rinv) {
  __shared__ float mxs[4][16], sms[4][16];
  int wave = threadIdx.x >> 6, lane = threadIdx.x & 63;
  int b = blockIdx.y;
  int n0 = blockIdx.x * 16;
  int col = lane & 15, g = lane >> 4;
  const u16* qbh = Qh + (size_t)b * kN * kD;
  const u16* qbl = Ql + (size_t)b * kN * kD;
  bf16x8 ah = *(const bf16x8*)(qbh + (size_t)(n0 + col) * kD + g * 8);
  bf16x8 al = *(const bf16x8*)(qbl + (size_t)(n0 + col) * kD + g * 8);
  float mx[4] = {-3.0e38f, -3.0e38f, -3.0e38f, -3.0e38f};
  float sm[4] = {0.f, 0.f, 0.f, 0.f};
#pragma unroll 1
  for (int m0 = wave * 16; m0 < kN; m0 += 64) {
    bf16x8 bh = *(const bf16x8*)(qbh + (size_t)(m0 + col) * kD + g * 8);
    bf16x8 bl = *(const bf16x8*)(qbl + (size_t)(m0 + col) * kD + g * 8);
    f32x4 s = {};
    s = mfma3(ah, al, bh, bl, s);
#pragma unroll
    for (int r = 0; r < 4; ++r) {
      float nm = fmaxf(mx[r], s[r]);
      sm[r] = sm[r] * fexp2((mx[r] - nm) * kL2E) + fexp2((s[r] - nm) * kL2E);
      mx[r] = nm;
    }
  }
#pragma unroll
  for (int o = 1; o < 16; o <<= 1) {
#pragma unroll
    for (int r = 0; r < 4; ++r) {
      float Mo = __shfl_xor(mx[r], o, 64);
      float So = __shfl_xor(sm[r], o, 64);
      float nm = fmaxf(mx[r], Mo);
      sm[r] = sm[r] * fexp2((mx[r] - nm) * kL2E) + So * fexp2((Mo - nm) * kL2E);
      mx[r] = nm;
    }
  }
  if (col == 0) {
#pragma unroll
    for (int r = 0; r < 4; ++r) {
      mxs[wave][4 * g + r] = mx[r];
      sms[wave][4 * g + r] = sm[r];
    }
  }
  __syncthreads();
  if (threadIdx.x < 16) {
    int t = threadIdx.x;
    float M = mxs[0][t], S = sms[0][t];
#pragma unroll
    for (int w = 1; w < 4; ++w) {
      float Mo = mxs[w][t], So = sms[w][t];
      float nm = fmaxf(M, Mo);
      S = S * fexp2((M - nm) * kL2E) + So * fexp2((Mo - nm) * kL2E);
      M = nm;
    }
    rm2[(size_t)b * kN + n0 + t] = M * kL2E;
    rinv[(size_t)b * kN + n0 + t] = 1.0f / S;
  }
}

// ---------------- pass2 v7: block m-32, 2 m-frags/wave (V register-reuse),
// raw v_exp_f32 + u32 word-packed P-split. No in-loop barriers; LDS end-combine.
__global__ __launch_bounds__(256) void pass2_kernel(
    const u16* __restrict__ Qh, const u16* __restrict__ Ql,
    const u16* __restrict__ Vph, const u16* __restrict__ Vpl,
    const float* __restrict__ rm2, const float* __restrict__ rinv,
    const u16* __restrict__ xh, const u16* __restrict__ xl,
    u16* __restrict__ yth, u16* __restrict__ ytl) {
  __shared__ f32x4 accs[4][8][64];
  __shared__ float csl[2][4][16];
  int wave = threadIdx.x >> 6, lane = threadIdx.x & 63;
  int b = blockIdx.y;
  int m0 = blockIdx.x * 32;
  int col = lane & 15, g = lane >> 4;
  const u16* qbh = Qh + (size_t)b * kN * kD;
  const u16* qbl = Ql + (size_t)b * kN * kD;
  const float* rmb = rm2 + (size_t)b * kN;
  const float* rib = rinv + (size_t)b * kN;
  bf16x8 bmh0 = *(const bf16x8*)(qbh + (size_t)(m0 + col) * kD + g * 8);
  bf16x8 bml0 = *(const bf16x8*)(qbl + (size_t)(m0 + col) * kD + g * 8);
  bf16x8 bmh1 = *(const bf16x8*)(qbh + (size_t)(m0 + 16 + col) * kD + g * 8);
  bf16x8 bml1 = *(const bf16x8*)(qbl + (size_t)(m0 + 16 + col) * kD + g * 8);
  const u16* vbh = Vph + (size_t)b * (kN / 32) * 4096;
  const u16* vbl = Vpl + (size_t)b * (kN / 32) * 4096;
  f32x4 accA[8] = {}, accB[8] = {};
  float csA = 0.f, csB = 0.f;
#pragma unroll 1
  for (int nn = wave * 32; nn < kN; nn += 128) {
    bf16x8 ah0 = *(const bf16x8*)(qbh + (size_t)(nn + col) * kD + g * 8);
    bf16x8 al0 = *(const bf16x8*)(qbl + (size_t)(nn + col) * kD + g * 8);
    bf16x8 ah1 = *(const bf16x8*)(qbh + (size_t)(nn + 16 + col) * kD + g * 8);
    bf16x8 al1 = *(const bf16x8*)(qbl + (size_t)(nn + 16 + col) * kD + g * 8);
    f32x4 sA0 = {}, sA1 = {}, sB0 = {}, sB1 = {};
    sA0 = mfma3(ah0, al0, bmh0, bml0, sA0);
    sA1 = mfma3(ah1, al1, bmh0, bml0, sA1);
    sB0 = mfma3(ah0, al0, bmh1, bml1, sB0);
    sB1 = mfma3(ah1, al1, bmh1, bml1, sB1);
    float pA[8], pB[8];
#pragma unroll
    for (int r = 0; r < 4; ++r) {
      float e0 = rmb[nn + 4 * g + r], i0 = rib[nn + 4 * g + r];
      float e1 = rmb[nn + 16 + 4 * g + r], i1 = rib[nn + 16 + 4 * g + r];
      pA[r] = fexp2(sA0[r] * kL2E - e0) * i0;
      pA[r + 4] = fexp2(sA1[r] * kL2E - e1) * i1;
      pB[r] = fexp2(sB0[r] * kL2E - e0) * i0;
      pB[r + 4] = fexp2(sB1[r] * kL2E - e1) * i1;
      csA += pA[r] + pA[r + 4];
      csB += pB[r] + pB[r + 4];
    }
    u32x4 Ahw, Alw, Bhw, Blw;
#pragma unroll
    for (int k2 = 0; k2 < 4; ++k2) {
      u32 h0, l0, h1, l1;
      splitpair(pA[2 * k2], pA[2 * k2 + 1], h0, l0);
      splitpair(pB[2 * k2], pB[2 * k2 + 1], h1, l1);
      Ahw[k2] = h0; Alw[k2] = l0;
      Bhw[k2] = h1; Blw[k2] = l1;
    }
    bf16x8 bAh = __builtin_bit_cast(bf16x8, Ahw);
    bf16x8 bAl = __builtin_bit_cast(bf16x8, Alw);
    bf16x8 bBh = __builtin_bit_cast(bf16x8, Bhw);
    bf16x8 bBl = __builtin_bit_cast(bf16x8, Blw);
    size_t vtile = (size_t)(nn >> 5) * 4096;
#pragma unroll
    for (int ct = 0; ct < 8; ++ct) {
      size_t off = vtile + ((size_t)ct * 64 + lane) * 8;
      bf16x8 a8h = *(const bf16x8*)(vbh + off);
      bf16x8 a8l = *(const bf16x8*)(vbl + off);
      accA[ct] = mfma3(a8h, a8l, bAh, bAl, accA[ct]);
      accB[ct] = mfma3(a8h, a8l, bBh, bBl, accB[ct]);
    }
  }
  csA += __shfl_xor(csA, 16, 64);
  csA += __shfl_xor(csA, 32, 64);
  csB += __shfl_xor(csB, 16, 64);
  csB += __shfl_xor(csB, 32, 64);
  if (lane < 16) {
    csl[0][wave][lane] = csA;
    csl[1][wave][lane] = csB;
  }
  // ---- phase A combine + write (rows m0+col)
#pragma unroll
  for (int ct = 0; ct < 8; ++ct) accs[wave][ct][lane] = accA[ct];
  __syncthreads();
  {
    float inv = 1.0f / (1e-9f + csl[0][0][col] + csl[0][1][col] + csl[0][2][col] + csl[0][3][col]);
    const u16* xrh = xh + ((size_t)b * kN + m0 + col) * kC;
    const u16* xrl = xl + ((size_t)b * kN + m0 + col) * kC;
#pragma unroll
    for (int i = 0; i < 2; ++i) {
      int ct = wave * 2 + i;
      f32x4 a = accs[0][ct][lane];
      a += accs[1][ct][lane];
      a += accs[2][ct][lane];
      a += accs[3][ct][lane];
      bf16x4 xvh = *(const bf16x4*)(xrh + ct * 16 + 4 * g);
      bf16x4 xvl = *(const bf16x4*)(xrl + ct * 16 + 4 * g);
#pragma unroll
      for (int r = 0; r < 4; ++r) {
        float xv = bf2f((u16)xvh[r]) + bf2f((u16)xvl[r]);
        float y = xv - a[r] * inv;
        u16 hh, ll;
        split2(y, hh, ll);
        size_t idx = ((size_t)b * kN + m0 + col) * kC + ct * 16 + 4 * g + r;
        yth[idx] = hh;
        ytl[idx] = ll;
      }
    }
  }
  __syncthreads();
  // ---- phase B combine + write (rows m0+16+col)
#pragma unroll
  for (int ct = 0; ct < 8; ++ct) accs[wave][ct][lane] = accB[ct];
  __syncthreads();
  {
    float inv = 1.0f / (1e-9f + csl[1][0][col] + csl[1][1][col] + csl[1][2][col] + csl[1][3][col]);
    const u16* xrh = xh + ((size_t)b * kN + m0 + 16 + col) * kC;
    const u16* xrl = xl + ((size_t)b * kN + m0 + 16 + col) * kC;
#pragma unroll
    for (int i = 0; i < 2; ++i) {
      int ct = wave * 2 + i;
      f32x4 a = accs[0][ct][lane];
      a += accs[1][ct][lane];
      a += accs[2][ct][lane];
      a += accs[3][ct][lane];
      bf16x4 xvh = *(const bf16x4*)(xrh + ct * 16 + 4 * g);
      bf16x4 xvl = *(const bf16x4*)(xrl + ct * 16 + 4 * g);
#pragma unroll
      for (int r = 0; r < 4; ++r) {
        float xv = bf2f((u16)xvh[r]) + bf2f((u16)xvl[r]);
        float y = xv - a[r] * inv;
        u16 hh, ll;
        split2(y, hh, ll);
        size_t idx = ((size_t)b * kN + m0 + 16 + col) * kC + ct * 16 + 4 * g + r;
        yth[idx] = hh;
        ytl[idx] = ll;
      }
    }
  }
}

// ---------------- conv GEMM: 4 waves x 2 output-tiles, 16 n-cols per block
__global__ __launch_bounds__(256) void tconv_kernel(
    const u16* __restrict__ inh, const u16* __restrict__ inl,
    const u16* __restrict__ wh, const u16* __restrict__ wl,
    const float* __restrict__ bias, float* __restrict__ u,
    long ustride, long uoff) {
  int wave = threadIdx.x >> 6, lane = threadIdx.x & 63;
  int b = blockIdx.y;
  int n0 = blockIdx.x * 16;
  int col = lane & 15, g = lane >> 4;
  f32x4 acc[2] = {};
  const u16* xrh = inh + ((size_t)b * kN + n0 + col) * kC + g * 8;
  const u16* xrl = inl + ((size_t)b * kN + n0 + col) * kC + g * 8;
#pragma unroll
  for (int kk = 0; kk < 4; ++kk) {
    bf16x8 bh = *(const bf16x8*)(xrh + kk * 32);
    bf16x8 bl = *(const bf16x8*)(xrl + kk * 32);
#pragma unroll
    for (int i = 0; i < 2; ++i) {
      int ot = wave * 2 + i;
      bf16x8 ah = *(const bf16x8*)(wh + (size_t)(ot * 16 + col) * kC + kk * 32 + g * 8);
      bf16x8 al = *(const bf16x8*)(wl + (size_t)(ot * 16 + col) * kC + kk * 32 + g * 8);
      acc[i] = mfma3(ah, al, bh, bl, acc[i]);
    }
  }
#pragma unroll
  for (int i = 0; i < 2; ++i) {
    int ot = wave * 2 + i;
#pragma unroll
    for (int r = 0; r < 4; ++r) {
      int c = ot * 16 + 4 * g + r;
      float v = acc[i][r] + (bias ? bias[c] : 0.f);
      u[(size_t)b * ustride + uoff + (size_t)c * kN + n0 + col] = v;
    }
  }
}

// ---------------- BN stats, SINGLE-PASS fp64 (no cancellation: double has 53 bits)
__global__ __launch_bounds__(256) void bn_stats_kernel(const float* __restrict__ u,
                                                       long ustride, long uoff,
                                                       float* __restrict__ stat) {
  int c = blockIdx.x;
  __shared__ double reds[4], redss[4];
  double s = 0.0, ss = 0.0;
  for (int i = threadIdx.x; i < kB * kN; i += 256) {
    int b = i >> 12, n = i & (kN - 1);
    float v = u[(size_t)b * ustride + uoff + (size_t)c * kN + n];
    s += (double)v;
    ss += (double)v * (double)v;
  }
#pragma unroll
  for (int o = 1; o < 64; o <<= 1) {
    s += __shfl_xor(s, o, 64);
    ss += __shfl_xor(ss, o, 64);
  }
  int wid = threadIdx.x >> 6, lane = threadIdx.x & 63;
  if (lane == 0) { reds[wid] = s; redss[wid] = ss; }
  __syncthreads();
  if (threadIdx.x == 0) {
    double S = reds[0] + reds[1] + reds[2] + reds[3];
    double SS = redss[0] + redss[1] + redss[2] + redss[3];
    double mean = S / (double)(kB * kN);
    double var = SS / (double)(kB * kN) - mean * mean;
    if (var < 0.0) var = 0.0;
    stat[c] = (float)mean;
    stat[kC + c] = rsqrtf((float)var + 1e-5f);
  }
}

// ---------------- fused bn_final + next-layer prep:
// y = relu(BN(u)) [+ h + e]; out = y; xh/xl = split(y + e)  (transpose via LDS)
__global__ __launch_bounds__(256) void bnprep_kernel(
    const float* __restrict__ u, long ustride, long uoff,
    const float* __restrict__ stat,
    const float* __restrict__ g, const float* __restrict__ bb,
    const float* __restrict__ h, long hstride, long hoff, int use_res,
    const float* __restrict__ xyz, const float* __restrict__ pw,
    const float* __restrict__ pb,
    float* __restrict__ out, long ostride, long ooff,
    u16* __restrict__ xh, u16* __restrict__ xl) {
  __shared__ float t[32][33];
  int n0 = blockIdx.x * 32, c0 = blockIdx.y * 32, b = blockIdx.z;
  int tx = threadIdx.x & 31, ty = threadIdx.x >> 5;  // 32 x 8
  const float* xp = xyz + ((size_t)b * kN + n0 + tx) * 3;
  float xv0 = xp[0], xv1 = xp[1], xv2 = xp[2];
#pragma unroll
  for (int i = 0; i < 4; ++i) {
    int c = c0 + ty + i * 8;
    float e = pw[c * 3 + 0] * xv0 + pw[c * 3 + 1] * xv1 + pw[c * 3 + 2] * xv2 + pb[c];
    float y = (u[(size_t)b * ustride + uoff + (size_t)c * kN + n0 + tx] - stat[c]) *
                  stat[kC + c] * g[c] + bb[c];
    y = fmaxf(y, 0.f);
    if (use_res) y += h[(size_t)b * hstride + hoff + (size_t)c * kN + n0 + tx] + e;
    out[(size_t)b * ostride + ooff + (size_t)c * kN + n0 + tx] = y;
    t[ty + i * 8][tx] = y + e;  // next layer's xa
  }
  __syncthreads();
#pragma unroll
  for (int i = 0; i < 4; ++i) {
    int n = n0 + ty + i * 8, c = c0 + tx;
    u16 hh, ll;
    split2(t[tx][ty + i * 8], hh, ll);
    size_t idx = ((size_t)b * kN + n) * kC + c;
    xh[idx] = hh;
    xl[idx] = ll;
  }
}

extern "C" void kernel_launch(void* const* d_in, const int* in_sizes, int n_in,
                              void* d_out, int out_size, void* d_ws, size_t ws_size,
                              hipStream_t stream) {
  const float* x = (const float*)d_in[0];
  const float* xyz = (const float*)d_in[1];
  const float* conv1_w = (const float*)d_in[2];
  const float* bn1_g = (const float*)d_in[3];
  const float* bn1_b = (const float*)d_in[4];
  const float* pos_w = (const float*)d_in[5];
  const float* pos_b = (const float*)d_in[6];
  const float* sa_wqk = (const float*)d_in[7];
  const float* sa_wv = (const float*)d_in[8];
  const float* sa_bv = (const float*)d_in[9];
  const float* sa_wt = (const float*)d_in[10];
  const float* sa_bt = (const float*)d_in[11];
  const float* sa_bng = (const float*)d_in[12];
  const float* sa_bnb = (const float*)d_in[13];
  float* out = (float*)d_out;
  char* ws = (char*)d_ws;
  const size_t MB = (size_t)1 << 20;

  const size_t NEED = 28 * MB;
  if (ws_size < NEED) {
    float val = 100.0f + (float)(ws_size >> 20);
    sentinel_kernel<<<dim3((out_size + 255) / 256), dim3(256), 0, stream>>>(out, val, out_size);
    return;
  }

  u16* xh = (u16*)(ws);                  // [0,4MB)
  u16* xl = (u16*)(ws + 4 * MB);         // [4,8MB)
  u16* yth = (u16*)(ws + 8 * MB);        // [8,12MB)
  u16* ytl = (u16*)(ws + 12 * MB);       // [12,16MB)
  u16* Vph = (u16*)(ws + 16 * MB);       // [16,20MB)  packed V hi
  u16* Vpl = (u16*)(ws + 20 * MB);       // [20,24MB)  packed V lo
  u16* Qh = (u16*)(ws + 24 * MB);        // [24,25MB)
  u16* Ql = (u16*)(ws + 25 * MB);        // [25,26MB)
  u16* wa = (u16*)(ws + 26 * MB);        // weight split arena [26,27MB)
  size_t woff = 0;
  u16* c1h = wa + woff; woff += 16384;
  u16* c1l = wa + woff; woff += 16384;
  u16* qkh = wa + woff; woff += 5 * 32 * 128;
  u16* qkl = wa + woff; woff += 5 * 32 * 128;
  u16* wvh = wa + woff; woff += 5 * 128 * 128;
  u16* wvl = wa + woff; woff += 5 * 128 * 128;
  u16* wth = wa + woff; woff += 5 * 128 * 128;
  u16* wtl = wa + woff; woff += 5 * 128 * 128;
  float* rm2 = (float*)(ws + 27 * MB);
  float* rinv = (float*)(ws + 27 * MB + 65536);
  float* stat = (float*)(ws + 27 * MB + 131072);

  dim3 blk(256);

  cvt_split_kernel<<<dim3(64), blk, 0, stream>>>(conv1_w, c1h, c1l, 16384);
  cvt_split_kernel<<<dim3(80), blk, 0, stream>>>(sa_wqk, qkh, qkl, 20480);
  cvt_split_kernel<<<dim3(320), blk, 0, stream>>>(sa_wv, wvh, wvl, 81920);
  cvt_split_kernel<<<dim3(320), blk, 0, stream>>>(sa_wt, wth, wtl, 81920);

  const long sbo = (long)kCO * kN;
  const long slice = (long)kC * kN;
  const long h0off = 4 * slice;  // h0 parked in layer-4 slice (dead after layer-0 reads)

  // ---- setup: conv1 + BN + relu -> h0; bnprep also emits layer-0 xa (h0 + emb)
  prep_kernel<<<dim3(kN / 32, kC / 32, kB), blk, 0, stream>>>(x, slice, 0, xh, xl);
  tconv_kernel<<<dim3(kN / 16, kB), blk, 0, stream>>>(
      xh, xl, c1h, c1l, nullptr, out, sbo, 0);
  bn_stats_kernel<<<dim3(kC), blk, 0, stream>>>(out, sbo, 0, stat);
  bnprep_kernel<<<dim3(kN / 32, kC / 32, kB), blk, 0, stream>>>(
      out, sbo, 0, stat, bn1_g, bn1_b, nullptr, 0, 0, 0, xyz, pos_w, pos_b,
      out, sbo, h0off, xh, xl);

  long hoff = h0off;
  for (int i = 0; i < kL; ++i) {
    long uoff = (long)i * slice;  // layer-i pre-BN u lives in out slice i (in-place BN)
    qv_kernel<<<dim3(kN / 16, kB), dim3(320), 0, stream>>>(
        xh, xl, qkh + (size_t)i * kD * kC, qkl + (size_t)i * kD * kC,
        wvh + (size_t)i * kC * kC, wvl + (size_t)i * kC * kC,
        sa_bv + (size_t)i * kC, Qh, Ql, Vph, Vpl);
    pass1_kernel<<<dim3(kN / 16, kB), blk, 0, stream>>>(Qh, Ql, rm2, rinv);
    pass2_kernel<<<dim3(kN / 32, kB), blk, 0, stream>>>(
        Qh, Ql, Vph, Vpl, rm2, rinv, xh, xl, yth, ytl);
    tconv_kernel<<<dim3(kN / 16, kB), blk, 0, stream>>>(
        yth, ytl, wth + (size_t)i * kC * kC, wtl + (size_t)i * kC * kC,
        sa_bt + (size_t)i * kC, out, sbo, uoff);
    bn_stats_kernel<<<dim3(kC), blk, 0, stream>>>(out, sbo, uoff, stat);
    bnprep_kernel<<<dim3(kN / 32, kC / 32, kB), blk, 0, stream>>>(
        out, sbo, uoff, stat, sa_bng + (size_t)i * kC, sa_bnb + (size_t)i * kC,
        out, sbo, hoff, 1, xyz, pos_w, pos_b, out, sbo, uoff, xh, xl);
    hoff = uoff;
  }
}